// Round 10
// baseline (32.569 us; speedup 1.0000x reference)
//
#include <hip/hip_runtime.h>

// 4-level MoE routing loss, B=8, H=1024, ROUTE=64, 16x16 patches/level.
// d_in: out0, gt0, out1, gt1, out2, gt2, out3, gt3   (all fp32)
// d_out (fp32 flat): [0] loss | [1..8388609) label_patch (8,1024,1024)
//   | [+2048) moe_label as float | [+8192) score (8,4,16,16)
// ws: double lossTerm[2048] @0 (16KB).
//
// R10: ONE WAVE = ONE PATCH. 128-thr blocks (2 independent waves, no
// __syncthreads, no LDS). Cross-lane reduce = 6-round __shfl_xor butterfly;
// every lane ends with the block totals and computes score/argmin
// redundantly (wave-uniform, no broadcast). Each wave flows straight from
// phase 1 (reads) into phase 2 (stores) independently -> no lockstep
// read-burst/write-burst phases, no rendezvous serialization.
// Keeps R9's XCD row-swizzle patch mapping and R6/R9 store layout
// (3/60/1 row split: aligned quads at lab[3+4j..6+4j]).
// Loss: per-patch lossTerm -> 1-block deterministic reduce (no atomics;
// returning hot-line atomics falsified in R4/R8).

#define NPATCH 2048

__global__ __launch_bounds__(128) void fused_kernel(
    const float* __restrict__ out0, const float* __restrict__ gt0,
    const float* __restrict__ out1, const float* __restrict__ gt1,
    const float* __restrict__ out2, const float* __restrict__ gt2,
    const float* __restrict__ out3, const float* __restrict__ gt3,
    float* __restrict__ scoreOut,   // (B,4,16,16)
    float* __restrict__ moeF,       // moe_label as float
    float* __restrict__ lab,        // label_patch base (d_out+1)
    double* __restrict__ lossTerm)  // ws [2048]
{
    const int w = threadIdx.x >> 6;            // wave in block
    const int lane = threadIdx.x & 63;
    const int pp = (blockIdx.x << 1) | w;      // swizzled patch index
    const int px = pp >> 7;                    // 0..15
    const int row = pp & 127;                  // b*16 + py (XCD row-swizzle)
    const int b = row >> 4;
    const int py = row & 15;
    const int l = (py << 4) | px;
    const int p = (b << 8) | l;                // logical patch id

    float e0 = 0.f, g0 = 0.f, e1 = 0.f, g1 = 0.f;
    float e2 = 0.f, g2 = 0.f, e3 = 0.f, g3 = 0.f;

    // ---- phase 1: per-level sums (wave-local, 64 lanes) ----
    // level 0: 64x64 = 1024 float4-pairs, 16 per lane
    {
        const size_t base = (size_t)b * 1048576;
        const int rb = py << 6, cb = px << 6;
        #pragma unroll 4
        for (int it = 0; it < 16; ++it) {
            int idx = (it << 6) | lane;
            int r = idx >> 4, c = (idx & 15) << 2;
            size_t off = base + (size_t)(rb + r) * 1024 + (cb + c);
            float4 o = *(const float4*)(out0 + off);
            float4 q = *(const float4*)(gt0 + off);
            float dx = o.x - q.x, dy = o.y - q.y, dz = o.z - q.z, dw = o.w - q.w;
            e0 += dx * dx + dy * dy + dz * dz + dw * dw;
            g0 += q.x + q.y + q.z + q.w;
        }
    }
    // level 1: 32x32 = 256 float4-pairs, 4 per lane
    {
        const size_t base = (size_t)b * 262144;
        const int rb = py << 5, cb = px << 5;
        #pragma unroll
        for (int it = 0; it < 4; ++it) {
            int idx = (it << 6) | lane;
            int r = idx >> 3, c = (idx & 7) << 2;
            size_t off = base + (size_t)(rb + r) * 512 + (cb + c);
            float4 o = *(const float4*)(out1 + off);
            float4 q = *(const float4*)(gt1 + off);
            float dx = o.x - q.x, dy = o.y - q.y, dz = o.z - q.z, dw = o.w - q.w;
            e1 += dx * dx + dy * dy + dz * dz + dw * dw;
            g1 += q.x + q.y + q.z + q.w;
        }
    }
    // level 2: 16x16 = 64 float4-pairs, 1 per lane
    {
        const size_t base = (size_t)b * 65536;
        int r = lane >> 2, c = (lane & 3) << 2;
        size_t off = base + (size_t)((py << 4) + r) * 256 + ((px << 4) + c);
        float4 o = *(const float4*)(out2 + off);
        float4 q = *(const float4*)(gt2 + off);
        float dx = o.x - q.x, dy = o.y - q.y, dz = o.z - q.z, dw = o.w - q.w;
        e2 = dx * dx + dy * dy + dz * dz + dw * dw;
        g2 = q.x + q.y + q.z + q.w;
    }
    // level 3: 8x8 = 16 float4-pairs; lanes load (lane&15), mask to lane<16
    {
        const size_t base = (size_t)b * 16384;
        int tt = lane & 15;
        int r = tt >> 1, c = (tt & 1) << 2;
        size_t off = base + (size_t)((py << 3) + r) * 128 + ((px << 3) + c);
        float4 o = *(const float4*)(out3 + off);
        float4 q = *(const float4*)(gt3 + off);
        float dx = o.x - q.x, dy = o.y - q.y, dz = o.z - q.z, dw = o.w - q.w;
        float e = dx * dx + dy * dy + dz * dz + dw * dw;
        float g = q.x + q.y + q.z + q.w;
        bool act = (lane < 16);
        e3 = act ? e : 0.f;
        g3 = act ? g : 0.f;
    }

    // ---- butterfly reduce: all 64 lanes end with the totals ----
    #pragma unroll
    for (int s = 1; s < 64; s <<= 1) {
        e0 += __shfl_xor(e0, s, 64);  g0 += __shfl_xor(g0, s, 64);
        e1 += __shfl_xor(e1, s, 64);  g1 += __shfl_xor(g1, s, 64);
        e2 += __shfl_xor(e2, s, 64);  g2 += __shfl_xor(g2, s, 64);
        e3 += __shfl_xor(e3, s, 64);  g3 += __shfl_xor(g3, s, 64);
    }

    // every lane computes score/argmin redundantly (wave-uniform)
    float E[4] = {e0, e1, e2, e3};
    float G[4] = {g0, g1, g2, g3};
    float S[4];
    #pragma unroll
    for (int i = 0; i < 4; ++i) {
        float kk = (float)((64 >> i) * (64 >> i));
        S[i] = E[i] / kk + E[i] / (G[i] + 1e-10f);
    }
    int m = 0; float best = S[0];
    #pragma unroll
    for (int i = 1; i < 4; ++i)
        if (S[i] < best) { best = S[i]; m = i; }   // strict <, first-min

    if (lane == 0) {
        #pragma unroll
        for (int i = 0; i < 4; ++i)
            scoreOut[b * 1024 + i * 256 + l] = S[i];
        moeF[p] = (float)m;
        double t = (double)e0 / 8388608.0;
        if (m >= 1) t += (double)e1 / 2097152.0;
        if (m >= 2) t += (double)e2 / 524288.0;
        if (m >= 3) t += (double)e3 / 131072.0;
        lossTerm[p] = t;
    }

    // ---- phase 2: write own 64x64 label tile (wave-independent) ----
    // Row y starts at lab index R0 (R0%4==0); d_out = lab+1, so aligned
    // quads are lab[3+4j..6+4j] (j=0..14); remainders lab[R0+0..2], lab[R0+63].
    const size_t labBase = (size_t)b * 1048576 + (size_t)(py << 6) * 1024 + (px << 6);

    if (m == 0) {
        #pragma unroll 4
        for (int it = 0; it < 16; ++it) {
            int idx = (it << 6) | lane;
            int y = idx >> 4, j = idx & 15;
            size_t R0 = labBase + (size_t)y * 1024;
            if (j < 15) {
                int x = 3 + 4 * j;
                float4 v;
                v.x = gt0[R0 + x];
                v.y = gt0[R0 + x + 1];
                v.z = gt0[R0 + x + 2];
                v.w = gt0[R0 + x + 3];
                *(float4*)(lab + R0 + x) = v;
            } else {
                lab[R0]      = gt0[R0];
                lab[R0 + 1]  = gt0[R0 + 1];
                lab[R0 + 2]  = gt0[R0 + 2];
                lab[R0 + 63] = gt0[R0 + 63];
            }
        }
    } else {
        const int k = 64 >> m, pad = (64 - k) >> 1, W = 1024 >> m;
        const float* gt = (m == 1) ? gt1 : (m == 2) ? gt2 : gt3;
        const size_t gbase = (size_t)b * W * W + (size_t)(py * k) * W + px * k;
        #pragma unroll 4
        for (int it = 0; it < 16; ++it) {
            int idx = (it << 6) | lane;
            int y = idx >> 4, j = idx & 15;
            size_t R0 = labBase + (size_t)y * 1024;
            int iy = y - pad;
            bool rowIn = (unsigned)iy < (unsigned)k;
            const float* grow = gt + gbase + (size_t)iy * W;
            if (j < 15) {
                int x = 3 + 4 * j;
                float4 v;
                #pragma unroll
                for (int u = 0; u < 4; ++u) {
                    int ix = x + u - pad;
                    float vv = 0.2f;
                    if (rowIn && (unsigned)ix < (unsigned)k) vv = grow[ix];
                    ((float*)&v)[u] = vv;
                }
                *(float4*)(lab + R0 + x) = v;
            } else {
                #pragma unroll
                for (int u = 0; u < 3; ++u) {
                    int ix = u - pad;
                    float vv = 0.2f;
                    if (rowIn && (unsigned)ix < (unsigned)k) vv = grow[ix];
                    lab[R0 + u] = vv;
                }
                int ix = 63 - pad;
                float vv = 0.2f;
                if (rowIn && (unsigned)ix < (unsigned)k) vv = grow[ix];
                lab[R0 + 63] = vv;
            }
        }
    }
}

__global__ __launch_bounds__(256) void loss_kernel(
    const double* __restrict__ lossTerm, float* __restrict__ lossOut)
{
    double t = 0.0;
    for (int i = threadIdx.x; i < NPATCH; i += 256) t += lossTerm[i];
    for (int s = 32; s; s >>= 1) t += __shfl_down(t, s, 64);
    __shared__ double sd[4];
    const int wave = threadIdx.x >> 6, lane = threadIdx.x & 63;
    if (lane == 0) sd[wave] = t;
    __syncthreads();
    if (threadIdx.x == 0)
        lossOut[0] = (float)(sd[0] + sd[1] + sd[2] + sd[3]);
}

extern "C" void kernel_launch(void* const* d_in, const int* in_sizes, int n_in,
                              void* d_out, int out_size, void* d_ws, size_t ws_size,
                              hipStream_t stream) {
    const float* out0 = (const float*)d_in[0];
    const float* gt0  = (const float*)d_in[1];
    const float* out1 = (const float*)d_in[2];
    const float* gt1  = (const float*)d_in[3];
    const float* out2 = (const float*)d_in[4];
    const float* gt2  = (const float*)d_in[5];
    const float* out3 = (const float*)d_in[6];
    const float* gt3  = (const float*)d_in[7];

    float* o = (float*)d_out;
    float* lossOut  = o;
    float* labOut   = o + 1;
    float* moeFOut  = o + 8388609;
    float* scoreOut = o + 8390657;

    double* lossTerm = (double*)d_ws;

    fused_kernel<<<NPATCH / 2, 128, 0, stream>>>(
        out0, gt0, out1, gt1, out2, gt2, out3, gt3,
        scoreOut, moeFOut, labOut, lossTerm);
    loss_kernel<<<1, 256, 0, stream>>>(lossTerm, lossOut);
}